// Round 2
// baseline (15587.042 us; speedup 1.0000x reference)
//
#include <hip/hip_runtime.h>
#include <hip/hip_cooperative_groups.h>
#include <cstdint>
#include <math.h>

namespace cg = cooperative_groups;

#define B_  64
#define L_  256
#define V_  256
#define E_  256
#define H_  1024
#define H3  3072

typedef __bf16 bf16x8 __attribute__((ext_vector_type(8)));
typedef float  f32x4  __attribute__((ext_vector_type(4)));

__device__ __forceinline__ unsigned short f2bf(float f) {
    union { float f; unsigned u; } v; v.f = f;
    unsigned r = v.u + 0x7fffu + ((v.u >> 16) & 1u);   // round-to-nearest-even
    return (unsigned short)(r >> 16);
}
__device__ __forceinline__ float bf2f(unsigned short u) {
    union { unsigned u; float f; } v; v.u = ((unsigned)u) << 16;
    return v.f;
}

// ---- prep: fp32 [rows][cols] -> bf16 [cols][rows] (N-major for B-fragments) ----
__global__ void prep_transpose(const float* __restrict__ src,
                               unsigned short* __restrict__ dst,
                               int rows, int cols) {
    int idx = blockIdx.x * 256 + threadIdx.x;
    if (idx >= rows * cols) return;
    int n = idx / rows;
    int k = idx % rows;
    dst[idx] = f2bf(src[(size_t)k * cols + n]);
}

// ---- prep: embedding fp32->bf16 ----
__global__ void prep_misc(const float* __restrict__ emb,
                          unsigned short* __restrict__ embB) {
    int idx = blockIdx.x * 256 + threadIdx.x;   // 65536 = V*E
    embB[idx] = f2bf(emb[idx]);
}

// ---- phase 1: xw[t][b][3H] = emb[tok[b,t]] @ Wi   (M=16384, K=256, N=3072) ----
// NOTE: output layout is time-major [L][B][3H] so the recurrence step reads are dense.
__global__ __launch_bounds__(256) void xw_gemm(const int* __restrict__ tokens,
                                               const unsigned short* __restrict__ embB,
                                               const unsigned short* __restrict__ WiT,
                                               unsigned short* __restrict__ xw) {
    int ntile = blockIdx.x;          // 48 tiles of 64 cols
    int mtile = blockIdx.y;          // 256 tiles of 64 rows
    int wave = threadIdx.x >> 6, lane = threadIdx.x & 63;
    int l16 = lane & 15, q = lane >> 4;

    int m = mtile * 64 + wave * 16 + l16;    // m = b*L + t
    int tok = tokens[m];
    const bf16x8* Arow = (const bf16x8*)(embB + (size_t)tok * E_);
    int n0 = ntile * 64;

    f32x4 acc[4] = {};
    for (int k0 = 0; k0 < E_; k0 += 32) {
        bf16x8 a = Arow[(k0 >> 3) + q];
#pragma unroll
        for (int j = 0; j < 4; j++) {
            const bf16x8* Brow = (const bf16x8*)(WiT + (size_t)(n0 + j*16 + l16) * E_);
            bf16x8 b = Brow[(k0 >> 3) + q];
            acc[j] = __builtin_amdgcn_mfma_f32_16x16x32_bf16(a, b, acc[j], 0, 0, 0);
        }
    }
    int mrow = mtile * 64 + wave * 16 + q * 4;   // m = b*L + t
#pragma unroll
    for (int j = 0; j < 4; j++) {
        int n = n0 + j * 16 + l16;
#pragma unroll
        for (int r = 0; r < 4; r++) {
            int mm = mrow + r;
            int b = mm >> 8, t = mm & 255;
            xw[((size_t)t * B_ + b) * H3 + n] = f2bf(acc[j][r]);
        }
    }
}

// ---- phase 2: persistent cooperative GRU over all 256 steps ----
// grid = 256 blocks (btile = bid&3, jtile = bid>>2), block = 256 threads (4 waves).
// Wh B-fragments register-resident (96 VGPR/lane); h fp32 state register-resident.
__global__ __launch_bounds__(256, 1) void gru_persistent(
        unsigned short* __restrict__ hbuf0,
        unsigned short* __restrict__ hbuf1,
        const unsigned short* __restrict__ WhT,
        const float* __restrict__ bh,
        const unsigned short* __restrict__ xw,
        unsigned short* __restrict__ yB) {
    __shared__ f32x4 red[4][3][64];
    cg::grid_group grid = cg::this_grid();

    int bid = blockIdx.x;
    int btile = bid & 3;             // 4 tiles of 16 batches
    int jtile = bid >> 2;            // 64 tiles of 16 h-cols
    int wave = threadIdx.x >> 6, lane = threadIdx.x & 63;
    int l16 = lane & 15, q = lane >> 4;
    int b0 = btile * 16, j0 = jtile * 16;
    int kbase = wave * 256;          // K split across the 4 waves

    // ---- load register-resident Wh fragments (once) ----
    bf16x8 Wreg[3][8];
#pragma unroll
    for (int g = 0; g < 3; g++) {
        const bf16x8* Brow = (const bf16x8*)(WhT + (size_t)(g * H_ + j0 + l16) * H_);
#pragma unroll
        for (int kk = 0; kk < 8; kk++)
            Wreg[g][kk] = Brow[(kbase >> 3) + kk * 4 + q];
    }

    // ---- per-thread gate/bias/state registers ----
    int Lp  = threadIdx.x & 63;
    int reg = threadIdx.x >> 6;
    int b_local = (Lp >> 4) * 4 + reg;   // C row
    int j_local = Lp & 15;               // C col
    int b = b0 + b_local, jg = j0 + j_local;
    float bhr = bh[jg];
    float bhz = bh[H_ + jg];
    float bhn = bh[2 * H_ + jg];
    float hreg = 0.0f;                   // fp32 hidden state for (b, jg)

    // ---- zero-init the bf16 h buffer for step 0 ----
    hbuf0[(size_t)b * H_ + jg] = 0;
    __threadfence();
    grid.sync();

    unsigned short* hcur = hbuf0;
    unsigned short* hnxt = hbuf1;

    for (int t = 0; t < L_; t++) {
        // prefetch this step's input-gate values (independent of MFMA chain)
        size_t xoff = ((size_t)t * B_ + b) * H3;
        float xr = bf2f(xw[xoff + jg]);
        float xz = bf2f(xw[xoff + H_ + jg]);
        float xn = bf2f(xw[xoff + 2 * H_ + jg]);

        // ---- h @ Wh for this block's 16 batches x (3x16) gate cols ----
        const unsigned short* Abase = hcur + (size_t)(b0 + l16) * H_ + kbase;
        f32x4 acc[3] = {};
#pragma unroll
        for (int kk = 0; kk < 8; kk++) {
            bf16x8 a = *(const bf16x8*)(Abase + kk * 32 + q * 8);
#pragma unroll
            for (int g = 0; g < 3; g++)
                acc[g] = __builtin_amdgcn_mfma_f32_16x16x32_bf16(a, Wreg[g][kk], acc[g], 0, 0, 0);
        }
#pragma unroll
        for (int g = 0; g < 3; g++) red[wave][g][lane] = acc[g];
        __syncthreads();

        float gh0 = red[0][0][Lp][reg] + red[1][0][Lp][reg] + red[2][0][Lp][reg] + red[3][0][Lp][reg];
        float gh1 = red[0][1][Lp][reg] + red[1][1][Lp][reg] + red[2][1][Lp][reg] + red[3][1][Lp][reg];
        float gh2 = red[0][2][Lp][reg] + red[1][2][Lp][reg] + red[2][2][Lp][reg] + red[3][2][Lp][reg];

        float r = 1.0f / (1.0f + __expf(-(xr + gh0 + bhr)));
        float z = 1.0f / (1.0f + __expf(-(xz + gh1 + bhz)));
        float n = tanhf(xn + r * (gh2 + bhn));
        float hnew = (1.0f - z) * n + z * hreg;
        hreg = hnew;

        unsigned short hb = f2bf(hnew);
        hnxt[(size_t)b * H_ + jg] = hb;
        yB[((size_t)b * L_ + t) * H_ + jg] = hb;

        __threadfence();
        grid.sync();

        unsigned short* tmp = hcur; hcur = hnxt; hnxt = tmp;
    }
}

// ---- phase 3: logits[m][v] = y[m] @ Wout + bout   (M=16384, K=1024, N=256) ----
__global__ __launch_bounds__(256) void out_gemm(const unsigned short* __restrict__ yB,
                                                const unsigned short* __restrict__ WoutT,
                                                const float* __restrict__ bout,
                                                float* __restrict__ out) {
    int ntile = blockIdx.x;          // 4 tiles of 64 cols
    int mtile = blockIdx.y;          // 256 tiles of 64 rows
    int wave = threadIdx.x >> 6, lane = threadIdx.x & 63;
    int l16 = lane & 15, q = lane >> 4;

    int m = mtile * 64 + wave * 16 + l16;
    const bf16x8* Arow = (const bf16x8*)(yB + (size_t)m * H_);
    int n0 = ntile * 64;

    f32x4 acc[4] = {};
    for (int k0 = 0; k0 < H_; k0 += 32) {
        bf16x8 a = Arow[(k0 >> 3) + q];
#pragma unroll
        for (int j = 0; j < 4; j++) {
            const bf16x8* Brow = (const bf16x8*)(WoutT + (size_t)(n0 + j*16 + l16) * H_);
            bf16x8 b = Brow[(k0 >> 3) + q];
            acc[j] = __builtin_amdgcn_mfma_f32_16x16x32_bf16(a, b, acc[j], 0, 0, 0);
        }
    }
    int mrow = mtile * 64 + wave * 16 + q * 4;
#pragma unroll
    for (int j = 0; j < 4; j++) {
        int n = n0 + j * 16 + l16;
        float bias = bout[n];
#pragma unroll
        for (int r = 0; r < 4; r++)
            out[(size_t)(mrow + r) * V_ + n] = acc[j][r] + bias;
    }
}

extern "C" void kernel_launch(void* const* d_in, const int* in_sizes, int n_in,
                              void* d_out, int out_size, void* d_ws, size_t ws_size,
                              hipStream_t stream) {
    const int*   tokens = (const int*)  d_in[0];
    const float* emb    = (const float*)d_in[1];
    const float* Wi     = (const float*)d_in[2];
    const float* Wh     = (const float*)d_in[3];
    const float* bh     = (const float*)d_in[4];
    const float* Wout   = (const float*)d_in[5];
    const float* bout   = (const float*)d_in[6];
    float* out = (float*)d_out;

    char* ws = (char*)d_ws;
    size_t off = 0;
    auto alloc = [&](size_t bytes) -> void* {
        void* p = ws + off;
        off += (bytes + 255) & ~(size_t)255;
        return p;
    };
    unsigned short* WhT   = (unsigned short*)alloc((size_t)H3 * H_ * 2);   // [3072][1024]
    unsigned short* WiT   = (unsigned short*)alloc((size_t)H3 * E_ * 2);   // [3072][256]
    unsigned short* WoutT = (unsigned short*)alloc((size_t)V_ * H_ * 2);   // [256][1024]
    unsigned short* embB  = (unsigned short*)alloc((size_t)V_ * E_ * 2);   // [256][256]
    unsigned short* xw    = (unsigned short*)alloc((size_t)L_ * B_ * H3 * 2); // 96 MB, [L][B][3H]
    unsigned short* yB    = (unsigned short*)alloc((size_t)B_ * L_ * H_ * 2); // 32 MB, [B][L][H]
    unsigned short* hb0   = (unsigned short*)alloc((size_t)B_ * H_ * 2);
    unsigned short* hb1   = (unsigned short*)alloc((size_t)B_ * H_ * 2);

    prep_transpose<<<(H_ * H3 + 255) / 256, 256, 0, stream>>>(Wh, WhT, H_, H3);
    prep_transpose<<<(E_ * H3 + 255) / 256, 256, 0, stream>>>(Wi, WiT, E_, H3);
    prep_transpose<<<(H_ * V_ + 255) / 256, 256, 0, stream>>>(Wout, WoutT, H_, V_);
    prep_misc<<<(V_ * E_) / 256, 256, 0, stream>>>(emb, embB);

    xw_gemm<<<dim3(48, 256), 256, 0, stream>>>(tokens, embB, WiT, xw);

    {
        unsigned short* a0 = hb0; unsigned short* a1 = hb1;
        const unsigned short* aW = WhT; const float* ab = bh;
        const unsigned short* ax = xw; unsigned short* ay = yB;
        void* args[] = {&a0, &a1, &aW, &ab, &ax, &ay};
        hipLaunchCooperativeKernel((void*)gru_persistent, dim3(256), dim3(256),
                                   args, 0, stream);
    }

    out_gemm<<<dim3(4, 256), 256, 0, stream>>>(yB, WoutT, bout, out);
}

// Round 3
// 4303.059 us; speedup vs baseline: 3.6223x; 3.6223x over previous
//
#include <hip/hip_runtime.h>
#include <cstdint>
#include <math.h>

#define B_  64
#define L_  256
#define V_  256
#define E_  256
#define H_  1024
#define H3  3072

typedef __bf16 bf16x8 __attribute__((ext_vector_type(8)));
typedef float  f32x4  __attribute__((ext_vector_type(4)));

__device__ __forceinline__ unsigned short f2bf(float f) {
    union { float f; unsigned u; } v; v.f = f;
    unsigned r = v.u + 0x7fffu + ((v.u >> 16) & 1u);   // round-to-nearest-even
    return (unsigned short)(r >> 16);
}
__device__ __forceinline__ float bf2f(unsigned short u) {
    union { unsigned u; float f; } v; v.u = ((unsigned)u) << 16;
    return v.f;
}

// ---- prep: fp32 [rows][cols] -> bf16 [cols][rows] (N-major for B-fragments) ----
__global__ void prep_transpose(const float* __restrict__ src,
                               unsigned short* __restrict__ dst,
                               int rows, int cols) {
    int idx = blockIdx.x * 256 + threadIdx.x;
    if (idx >= rows * cols) return;
    int n = idx / rows;
    int k = idx % rows;
    dst[idx] = f2bf(src[(size_t)k * cols + n]);
}

// ---- prep: embedding fp32->bf16, zero h0 (bf16), zero barrier words ----
__global__ void prep_misc(const float* __restrict__ emb,
                          unsigned short* __restrict__ embB,
                          unsigned short* __restrict__ h0b,
                          unsigned* __restrict__ bar) {
    int idx = blockIdx.x * 256 + threadIdx.x;   // 65536 = V*E = B*H
    embB[idx] = f2bf(emb[idx]);
    h0b[idx]  = 0;
    if (idx < 1024) bar[idx] = 0;
}

// ---- phase 1: xw[t][b][3H] = emb[tok[b,t]] @ Wi   (M=16384, K=256, N=3072) ----
__global__ __launch_bounds__(256) void xw_gemm(const int* __restrict__ tokens,
                                               const unsigned short* __restrict__ embB,
                                               const unsigned short* __restrict__ WiT,
                                               unsigned short* __restrict__ xw) {
    int ntile = blockIdx.x;          // 48 tiles of 64 cols
    int mtile = blockIdx.y;          // 256 tiles of 64 rows
    int wave = threadIdx.x >> 6, lane = threadIdx.x & 63;
    int l16 = lane & 15, q = lane >> 4;

    int m = mtile * 64 + wave * 16 + l16;    // m = b*L + t
    int tok = tokens[m];
    const bf16x8* Arow = (const bf16x8*)(embB + (size_t)tok * E_);
    int n0 = ntile * 64;

    f32x4 acc[4] = {};
    for (int k0 = 0; k0 < E_; k0 += 32) {
        bf16x8 a = Arow[(k0 >> 3) + q];
#pragma unroll
        for (int j = 0; j < 4; j++) {
            const bf16x8* Brow = (const bf16x8*)(WiT + (size_t)(n0 + j*16 + l16) * E_);
            bf16x8 b = Brow[(k0 >> 3) + q];
            acc[j] = __builtin_amdgcn_mfma_f32_16x16x32_bf16(a, b, acc[j], 0, 0, 0);
        }
    }
    int mrow = mtile * 64 + wave * 16 + q * 4;   // m = b*L + t
#pragma unroll
    for (int j = 0; j < 4; j++) {
        int n = n0 + j * 16 + l16;
#pragma unroll
        for (int r = 0; r < 4; r++) {
            int mm = mrow + r;
            int b = mm >> 8, t = mm & 255;
            xw[((size_t)t * B_ + b) * H3 + n] = f2bf(acc[j][r]);
        }
    }
}

// ---- hand-rolled per-group grid barrier (64 blocks per btile group) ----
// cnt at bar[g*64], gen at bar[g*64+32] -> 256B / 128B separation.
__device__ __forceinline__ void group_barrier(unsigned* cnt, unsigned* gen,
                                              unsigned nblk) {
    __syncthreads();
    if (threadIdx.x == 0) {
        __threadfence();   // release: write back this XCD's dirty L2 (h, y)
        unsigned g = __hip_atomic_load(gen, __ATOMIC_RELAXED, __HIP_MEMORY_SCOPE_AGENT);
        unsigned a = __hip_atomic_fetch_add(cnt, 1u, __ATOMIC_RELAXED, __HIP_MEMORY_SCOPE_AGENT);
        if (a == nblk - 1u) {
            __hip_atomic_store(cnt, 0u, __ATOMIC_RELAXED, __HIP_MEMORY_SCOPE_AGENT);
            __hip_atomic_store(gen, g + 1u, __ATOMIC_RELEASE, __HIP_MEMORY_SCOPE_AGENT);
        } else {
            while (__hip_atomic_load(gen, __ATOMIC_RELAXED, __HIP_MEMORY_SCOPE_AGENT) == g) {
                __builtin_amdgcn_s_sleep(1);
            }
        }
        __threadfence();   // acquire: invalidate stale L1/L2 before reading peers' h
    }
    __syncthreads();
}

// ---- phase 2: persistent cooperative GRU, custom barriers, Wh pinned in VGPRs ----
__global__ __launch_bounds__(256, 1) void gru_persistent(
        unsigned short* __restrict__ hbuf0,
        unsigned short* __restrict__ hbuf1,
        const unsigned short* __restrict__ WhT,
        const float* __restrict__ bh,
        const unsigned short* __restrict__ xw,
        unsigned short* __restrict__ yB,
        unsigned* __restrict__ bar) {
    __shared__ f32x4 red[4][3][64];

    int bid = blockIdx.x;
    int btile = bid & 3;             // 4 tiles of 16 batches (independent groups)
    int jtile = bid >> 2;            // 64 tiles of 16 h-cols
    int wave = threadIdx.x >> 6, lane = threadIdx.x & 63;
    int l16 = lane & 15, q = lane >> 4;
    int b0 = btile * 16, j0 = jtile * 16;
    int kbase = wave * 256;          // K split across the 4 waves

    unsigned* cnt = bar + btile * 64;
    unsigned* gen = bar + btile * 64 + 32;

    // ---- load Wh fragments once and PIN them in VGPRs (96 VGPRs/lane) ----
    bf16x8 Wreg[3][8];
#pragma unroll
    for (int g = 0; g < 3; g++) {
        const bf16x8* Brow = (const bf16x8*)(WhT + (size_t)(g * H_ + j0 + l16) * H_);
#pragma unroll
        for (int kk = 0; kk < 8; kk++) {
            Wreg[g][kk] = Brow[(kbase >> 3) + kk * 4 + q];
            asm volatile("" : "+v"(Wreg[g][kk]));   // opaque: forbid rematerialization
        }
    }

    // ---- per-thread gate mapping / biases / fp32 state ----
    int Lp  = threadIdx.x & 63;
    int reg = threadIdx.x >> 6;
    int b_local = (Lp >> 4) * 4 + reg;   // C row
    int j_local = Lp & 15;               // C col
    int b = b0 + b_local, jg = j0 + j_local;
    float bhr = bh[jg];
    float bhz = bh[H_ + jg];
    float bhn = bh[2 * H_ + jg];
    asm volatile("" : "+v"(bhr), "+v"(bhz), "+v"(bhn));
    float hreg = 0.0f;                   // fp32 hidden state for (b, jg)

    unsigned short* hcur = hbuf0;        // zeroed by prep_misc
    unsigned short* hnxt = hbuf1;

    for (int t = 0; t < L_; t++) {
        // prefetch this step's input-gate values (consumed after the MFMA section)
        size_t xoff = ((size_t)t * B_ + b) * H3;
        float xr = bf2f(xw[xoff + jg]);
        float xz = bf2f(xw[xoff + H_ + jg]);
        float xn = bf2f(xw[xoff + 2 * H_ + jg]);

        // ---- h @ Wh for this block's 16 batches x (3x16) gate cols ----
        const unsigned short* Abase = hcur + (size_t)(b0 + l16) * H_ + kbase;
        f32x4 acc[3] = {};
#pragma unroll
        for (int kk = 0; kk < 8; kk++) {
            bf16x8 a = *(const bf16x8*)(Abase + kk * 32 + q * 8);
#pragma unroll
            for (int g = 0; g < 3; g++)
                acc[g] = __builtin_amdgcn_mfma_f32_16x16x32_bf16(a, Wreg[g][kk], acc[g], 0, 0, 0);
        }
#pragma unroll
        for (int g = 0; g < 3; g++) red[wave][g][lane] = acc[g];
        __syncthreads();

        float gh0 = red[0][0][Lp][reg] + red[1][0][Lp][reg] + red[2][0][Lp][reg] + red[3][0][Lp][reg];
        float gh1 = red[0][1][Lp][reg] + red[1][1][Lp][reg] + red[2][1][Lp][reg] + red[3][1][Lp][reg];
        float gh2 = red[0][2][Lp][reg] + red[1][2][Lp][reg] + red[2][2][Lp][reg] + red[3][2][Lp][reg];

        float r = 1.0f / (1.0f + __expf(-(xr + gh0 + bhr)));
        float z = 1.0f / (1.0f + __expf(-(xz + gh1 + bhz)));
        float n = tanhf(xn + r * (gh2 + bhn));
        float hnew = (1.0f - z) * n + z * hreg;
        hreg = hnew;

        unsigned short hbv = f2bf(hnew);
        hnxt[(size_t)b * H_ + jg] = hbv;
        yB[((size_t)b * L_ + t) * H_ + jg] = hbv;

        group_barrier(cnt, gen, 64u);

        unsigned short* tmp = hcur; hcur = hnxt; hnxt = tmp;
    }
}

// ---- phase 3: logits[m][v] = y[m] @ Wout + bout   (M=16384, K=1024, N=256) ----
__global__ __launch_bounds__(256) void out_gemm(const unsigned short* __restrict__ yB,
                                                const unsigned short* __restrict__ WoutT,
                                                const float* __restrict__ bout,
                                                float* __restrict__ out) {
    int ntile = blockIdx.x;          // 4 tiles of 64 cols
    int mtile = blockIdx.y;          // 256 tiles of 64 rows
    int wave = threadIdx.x >> 6, lane = threadIdx.x & 63;
    int l16 = lane & 15, q = lane >> 4;

    int m = mtile * 64 + wave * 16 + l16;
    const bf16x8* Arow = (const bf16x8*)(yB + (size_t)m * H_);
    int n0 = ntile * 64;

    f32x4 acc[4] = {};
    for (int k0 = 0; k0 < H_; k0 += 32) {
        bf16x8 a = Arow[(k0 >> 3) + q];
#pragma unroll
        for (int j = 0; j < 4; j++) {
            const bf16x8* Brow = (const bf16x8*)(WoutT + (size_t)(n0 + j*16 + l16) * H_);
            bf16x8 b = Brow[(k0 >> 3) + q];
            acc[j] = __builtin_amdgcn_mfma_f32_16x16x32_bf16(a, b, acc[j], 0, 0, 0);
        }
    }
    int mrow = mtile * 64 + wave * 16 + q * 4;
#pragma unroll
    for (int j = 0; j < 4; j++) {
        int n = n0 + j * 16 + l16;
        float bias = bout[n];
#pragma unroll
        for (int r = 0; r < 4; r++)
            out[(size_t)(mrow + r) * V_ + n] = acc[j][r] + bias;
    }
}

extern "C" void kernel_launch(void* const* d_in, const int* in_sizes, int n_in,
                              void* d_out, int out_size, void* d_ws, size_t ws_size,
                              hipStream_t stream) {
    const int*   tokens = (const int*)  d_in[0];
    const float* emb    = (const float*)d_in[1];
    const float* Wi     = (const float*)d_in[2];
    const float* Wh     = (const float*)d_in[3];
    const float* bh     = (const float*)d_in[4];
    const float* Wout   = (const float*)d_in[5];
    const float* bout   = (const float*)d_in[6];
    float* out = (float*)d_out;

    char* ws = (char*)d_ws;
    size_t off = 0;
    auto alloc = [&](size_t bytes) -> void* {
        void* p = ws + off;
        off += (bytes + 255) & ~(size_t)255;
        return p;
    };
    unsigned short* WhT   = (unsigned short*)alloc((size_t)H3 * H_ * 2);   // [3072][1024]
    unsigned short* WiT   = (unsigned short*)alloc((size_t)H3 * E_ * 2);   // [3072][256]
    unsigned short* WoutT = (unsigned short*)alloc((size_t)V_ * H_ * 2);   // [256][1024]
    unsigned short* embB  = (unsigned short*)alloc((size_t)V_ * E_ * 2);   // [256][256]
    unsigned short* xw    = (unsigned short*)alloc((size_t)L_ * B_ * H3 * 2); // 96 MB, [L][B][3H]
    unsigned short* yB    = (unsigned short*)alloc((size_t)B_ * L_ * H_ * 2); // 32 MB, [B][L][H]
    unsigned short* hb0   = (unsigned short*)alloc((size_t)B_ * H_ * 2);
    unsigned short* hb1   = (unsigned short*)alloc((size_t)B_ * H_ * 2);
    unsigned*       bar   = (unsigned*)alloc(1024 * sizeof(unsigned));

    prep_transpose<<<(H_ * H3 + 255) / 256, 256, 0, stream>>>(Wh, WhT, H_, H3);
    prep_transpose<<<(E_ * H3 + 255) / 256, 256, 0, stream>>>(Wi, WiT, E_, H3);
    prep_transpose<<<(H_ * V_ + 255) / 256, 256, 0, stream>>>(Wout, WoutT, H_, V_);
    prep_misc<<<(V_ * E_) / 256, 256, 0, stream>>>(emb, embB, hb0, bar);

    xw_gemm<<<dim3(48, 256), 256, 0, stream>>>(tokens, embB, WiT, xw);

    {
        unsigned short* a0 = hb0; unsigned short* a1 = hb1;
        const unsigned short* aW = WhT; const float* ab = bh;
        const unsigned short* ax = xw; unsigned short* ay = yB;
        unsigned* abar = bar;
        void* args[] = {&a0, &a1, &aW, &ab, &ax, &ay, &abar};
        hipLaunchCooperativeKernel((void*)gru_persistent, dim3(256), dim3(256),
                                   args, 0, stream);
    }

    out_gemm<<<dim3(4, 256), 256, 0, stream>>>(yB, WoutT, bout, out);
}

// Round 4
// 1277.419 us; speedup vs baseline: 12.2020x; 3.3686x over previous
//
#include <hip/hip_runtime.h>
#include <cstdint>
#include <math.h>

#define B_  64
#define L_  256
#define V_  256
#define E_  256
#define H_  1024
#define H3  3072

typedef __bf16 bf16x8 __attribute__((ext_vector_type(8)));
typedef float  f32x4  __attribute__((ext_vector_type(4)));

__device__ __forceinline__ unsigned short f2bf(float f) {
    union { float f; unsigned u; } v; v.f = f;
    unsigned r = v.u + 0x7fffu + ((v.u >> 16) & 1u);   // round-to-nearest-even
    return (unsigned short)(r >> 16);
}
__device__ __forceinline__ float bf2f(unsigned short u) {
    union { unsigned u; float f; } v; v.u = ((unsigned)u) << 16;
    return v.f;
}

// ---- prep: fp32 [rows][cols] -> bf16 [cols][rows] (N-major for B-fragments) ----
__global__ void prep_transpose(const float* __restrict__ src,
                               unsigned short* __restrict__ dst,
                               int rows, int cols) {
    int idx = blockIdx.x * 256 + threadIdx.x;
    if (idx >= rows * cols) return;
    int n = idx / rows;
    int k = idx % rows;
    dst[idx] = f2bf(src[(size_t)k * cols + n]);
}

// ---- prep: embedding fp32->bf16, zero h0 (bf16), zero barrier words ----
__global__ void prep_misc(const float* __restrict__ emb,
                          unsigned short* __restrict__ embB,
                          unsigned short* __restrict__ h0b,
                          unsigned* __restrict__ bar) {
    int idx = blockIdx.x * 256 + threadIdx.x;   // 65536 = V*E = B*H
    embB[idx] = f2bf(emb[idx]);
    h0b[idx]  = 0;
    if (idx < 1024) bar[idx] = 0;
}

// ---- phase 1: xw[t][b][3H] = emb[tok[b,t]] @ Wi   (M=16384, K=256, N=3072) ----
__global__ __launch_bounds__(256) void xw_gemm(const int* __restrict__ tokens,
                                               const unsigned short* __restrict__ embB,
                                               const unsigned short* __restrict__ WiT,
                                               unsigned short* __restrict__ xw) {
    int ntile = blockIdx.x;          // 48 tiles of 64 cols
    int mtile = blockIdx.y;          // 256 tiles of 64 rows
    int wave = threadIdx.x >> 6, lane = threadIdx.x & 63;
    int l16 = lane & 15, q = lane >> 4;

    int m = mtile * 64 + wave * 16 + l16;    // m = b*L + t
    int tok = tokens[m];
    const bf16x8* Arow = (const bf16x8*)(embB + (size_t)tok * E_);
    int n0 = ntile * 64;

    f32x4 acc[4] = {};
    for (int k0 = 0; k0 < E_; k0 += 32) {
        bf16x8 a = Arow[(k0 >> 3) + q];
#pragma unroll
        for (int j = 0; j < 4; j++) {
            const bf16x8* Brow = (const bf16x8*)(WiT + (size_t)(n0 + j*16 + l16) * E_);
            bf16x8 b = Brow[(k0 >> 3) + q];
            acc[j] = __builtin_amdgcn_mfma_f32_16x16x32_bf16(a, b, acc[j], 0, 0, 0);
        }
    }
    int mrow = mtile * 64 + wave * 16 + q * 4;   // m = b*L + t
#pragma unroll
    for (int j = 0; j < 4; j++) {
        int n = n0 + j * 16 + l16;
#pragma unroll
        for (int r = 0; r < 4; r++) {
            int mm = mrow + r;
            int b = mm >> 8, t = mm & 255;
            xw[((size_t)t * B_ + b) * H3 + n] = f2bf(acc[j][r]);
        }
    }
}

// ---- fence-free per-group barrier: h traffic is cache-bypassing (sc0 sc1),
// so visibility needs only vmcnt drain (done by __syncthreads) + IC-coherent
// agent atomics. NO L2 writeback/invalidate -> Wh/xw stay cached. ----
__device__ __forceinline__ void group_barrier(unsigned* cnt, unsigned* gen,
                                              unsigned nblk) {
    __syncthreads();   // emits s_waitcnt vmcnt(0): all write-through h stores at IC
    if (threadIdx.x == 0) {
        unsigned g = __hip_atomic_load(gen, __ATOMIC_RELAXED, __HIP_MEMORY_SCOPE_AGENT);
        unsigned a = __hip_atomic_fetch_add(cnt, 1u, __ATOMIC_RELAXED, __HIP_MEMORY_SCOPE_AGENT);
        if (a == nblk - 1u) {
            __hip_atomic_store(cnt, 0u, __ATOMIC_RELAXED, __HIP_MEMORY_SCOPE_AGENT);
            __hip_atomic_store(gen, g + 1u, __ATOMIC_RELAXED, __HIP_MEMORY_SCOPE_AGENT);
        } else {
            while (__hip_atomic_load(gen, __ATOMIC_RELAXED, __HIP_MEMORY_SCOPE_AGENT) == g) {
                __builtin_amdgcn_s_sleep(1);
            }
        }
    }
    __syncthreads();
}

// ---- phase 2: persistent cooperative GRU, fence-free barriers ----
__global__ __launch_bounds__(256, 1) void gru_persistent(
        unsigned short* __restrict__ hbuf0,
        unsigned short* __restrict__ hbuf1,
        const unsigned short* __restrict__ WhT,
        const float* __restrict__ bh,
        const unsigned short* __restrict__ xw,
        unsigned short* __restrict__ yB,
        unsigned* __restrict__ bar) {
    __shared__ f32x4 red[4][3][64];

    int bid = blockIdx.x;
    int btile = bid & 3;             // 4 tiles of 16 batches (independent groups)
    int jtile = bid >> 2;            // 64 tiles of 16 h-cols
    int wave = threadIdx.x >> 6, lane = threadIdx.x & 63;
    int l16 = lane & 15, q = lane >> 4;
    int b0 = btile * 16, j0 = jtile * 16;
    int kbase = wave * 256;          // K split across the 4 waves

    unsigned* cnt = bar + btile * 64;
    unsigned* gen = bar + btile * 64 + 32;

    // ---- load Wh fragments once; pin so they stay register/AGPR-resident ----
    bf16x8 Wreg[3][8];
#pragma unroll
    for (int g = 0; g < 3; g++) {
        const bf16x8* Brow = (const bf16x8*)(WhT + (size_t)(g * H_ + j0 + l16) * H_);
#pragma unroll
        for (int kk = 0; kk < 8; kk++) {
            Wreg[g][kk] = Brow[(kbase >> 3) + kk * 4 + q];
            asm volatile("" : "+v"(Wreg[g][kk]));   // opaque: forbid rematerialization
        }
    }

    // ---- per-thread gate mapping / biases / fp32 state ----
    int Lp  = threadIdx.x & 63;
    int reg = threadIdx.x >> 6;
    int b_local = (Lp >> 4) * 4 + reg;   // C row
    int j_local = Lp & 15;               // C col
    int b = b0 + b_local, jg = j0 + j_local;
    float bhr = bh[jg];
    float bhz = bh[H_ + jg];
    float bhn = bh[2 * H_ + jg];
    asm volatile("" : "+v"(bhr), "+v"(bhz), "+v"(bhn));
    float hreg = 0.0f;                   // fp32 hidden state for (b, jg)

    unsigned short* hcur = hbuf0;        // zeroed by prep_misc
    unsigned short* hnxt = hbuf1;

    for (int t = 0; t < L_; t++) {
        // this step's input-gate values (cached loads; consumed after MFMA)
        size_t xoff = ((size_t)t * B_ + b) * H3;
        float xr = bf2f(xw[xoff + jg]);
        float xz = bf2f(xw[xoff + H_ + jg]);
        float xn = bf2f(xw[xoff + 2 * H_ + jg]);

        // ---- coherent (L1/L2-bypassing) loads of h A-fragments ----
        const unsigned short* Abase = hcur + (size_t)(b0 + l16) * H_ + kbase;
        bf16x8 a0, a1, a2, a3, a4, a5, a6, a7;
        {
            const unsigned short* p = Abase + q * 8;
            asm volatile("global_load_dwordx4 %0, %1, off sc0 sc1" : "=v"(a0) : "v"(p));
            asm volatile("global_load_dwordx4 %0, %1, off sc0 sc1" : "=v"(a1) : "v"(p + 32));
            asm volatile("global_load_dwordx4 %0, %1, off sc0 sc1" : "=v"(a2) : "v"(p + 64));
            asm volatile("global_load_dwordx4 %0, %1, off sc0 sc1" : "=v"(a3) : "v"(p + 96));
            asm volatile("global_load_dwordx4 %0, %1, off sc0 sc1" : "=v"(a4) : "v"(p + 128));
            asm volatile("global_load_dwordx4 %0, %1, off sc0 sc1" : "=v"(a5) : "v"(p + 160));
            asm volatile("global_load_dwordx4 %0, %1, off sc0 sc1" : "=v"(a6) : "v"(p + 192));
            asm volatile("global_load_dwordx4 %0, %1, off sc0 sc1" : "=v"(a7) : "v"(p + 224));
            asm volatile("s_waitcnt vmcnt(0)"
                         : "+v"(a0), "+v"(a1), "+v"(a2), "+v"(a3),
                           "+v"(a4), "+v"(a5), "+v"(a6), "+v"(a7)
                         :: "memory");
        }

        f32x4 acc[3] = {};
#pragma unroll
        for (int g = 0; g < 3; g++) {
            acc[g] = __builtin_amdgcn_mfma_f32_16x16x32_bf16(a0, Wreg[g][0], acc[g], 0, 0, 0);
            acc[g] = __builtin_amdgcn_mfma_f32_16x16x32_bf16(a1, Wreg[g][1], acc[g], 0, 0, 0);
            acc[g] = __builtin_amdgcn_mfma_f32_16x16x32_bf16(a2, Wreg[g][2], acc[g], 0, 0, 0);
            acc[g] = __builtin_amdgcn_mfma_f32_16x16x32_bf16(a3, Wreg[g][3], acc[g], 0, 0, 0);
            acc[g] = __builtin_amdgcn_mfma_f32_16x16x32_bf16(a4, Wreg[g][4], acc[g], 0, 0, 0);
            acc[g] = __builtin_amdgcn_mfma_f32_16x16x32_bf16(a5, Wreg[g][5], acc[g], 0, 0, 0);
            acc[g] = __builtin_amdgcn_mfma_f32_16x16x32_bf16(a6, Wreg[g][6], acc[g], 0, 0, 0);
            acc[g] = __builtin_amdgcn_mfma_f32_16x16x32_bf16(a7, Wreg[g][7], acc[g], 0, 0, 0);
        }
#pragma unroll
        for (int g = 0; g < 3; g++) red[wave][g][lane] = acc[g];
        __syncthreads();

        float gh0 = red[0][0][Lp][reg] + red[1][0][Lp][reg] + red[2][0][Lp][reg] + red[3][0][Lp][reg];
        float gh1 = red[0][1][Lp][reg] + red[1][1][Lp][reg] + red[2][1][Lp][reg] + red[3][1][Lp][reg];
        float gh2 = red[0][2][Lp][reg] + red[1][2][Lp][reg] + red[2][2][Lp][reg] + red[3][2][Lp][reg];

        float r = 1.0f / (1.0f + __expf(-(xr + gh0 + bhr)));
        float z = 1.0f / (1.0f + __expf(-(xz + gh1 + bhz)));
        float n = tanhf(xn + r * (gh2 + bhn));
        float hnew = (1.0f - z) * n + z * hreg;
        hreg = hnew;

        unsigned short hbv = f2bf(hnew);
        // coherent write-through h store (visible at IC once vmcnt retires)
        {
            unsigned short* hp = hnxt + (size_t)b * H_ + jg;
            unsigned hv32 = hbv;
            asm volatile("global_store_short %0, %1, off sc0 sc1"
                         :: "v"(hp), "v"(hv32) : "memory");
        }
        yB[((size_t)b * L_ + t) * H_ + jg] = hbv;   // cached; read after kernel end

        group_barrier(cnt, gen, 64u);

        unsigned short* tmp = hcur; hcur = hnxt; hnxt = tmp;
    }
}

// ---- phase 3: logits[m][v] = y[m] @ Wout + bout   (M=16384, K=1024, N=256) ----
__global__ __launch_bounds__(256) void out_gemm(const unsigned short* __restrict__ yB,
                                                const unsigned short* __restrict__ WoutT,
                                                const float* __restrict__ bout,
                                                float* __restrict__ out) {
    int ntile = blockIdx.x;          // 4 tiles of 64 cols
    int mtile = blockIdx.y;          // 256 tiles of 64 rows
    int wave = threadIdx.x >> 6, lane = threadIdx.x & 63;
    int l16 = lane & 15, q = lane >> 4;

    int m = mtile * 64 + wave * 16 + l16;
    const bf16x8* Arow = (const bf16x8*)(yB + (size_t)m * H_);
    int n0 = ntile * 64;

    f32x4 acc[4] = {};
    for (int k0 = 0; k0 < H_; k0 += 32) {
        bf16x8 a = Arow[(k0 >> 3) + q];
#pragma unroll
        for (int j = 0; j < 4; j++) {
            const bf16x8* Brow = (const bf16x8*)(WoutT + (size_t)(n0 + j*16 + l16) * H_);
            bf16x8 b = Brow[(k0 >> 3) + q];
            acc[j] = __builtin_amdgcn_mfma_f32_16x16x32_bf16(a, b, acc[j], 0, 0, 0);
        }
    }
    int mrow = mtile * 64 + wave * 16 + q * 4;
#pragma unroll
    for (int j = 0; j < 4; j++) {
        int n = n0 + j * 16 + l16;
        float bias = bout[n];
#pragma unroll
        for (int r = 0; r < 4; r++)
            out[(size_t)(mrow + r) * V_ + n] = acc[j][r] + bias;
    }
}

extern "C" void kernel_launch(void* const* d_in, const int* in_sizes, int n_in,
                              void* d_out, int out_size, void* d_ws, size_t ws_size,
                              hipStream_t stream) {
    const int*   tokens = (const int*)  d_in[0];
    const float* emb    = (const float*)d_in[1];
    const float* Wi     = (const float*)d_in[2];
    const float* Wh     = (const float*)d_in[3];
    const float* bh     = (const float*)d_in[4];
    const float* Wout   = (const float*)d_in[5];
    const float* bout   = (const float*)d_in[6];
    float* out = (float*)d_out;

    char* ws = (char*)d_ws;
    size_t off = 0;
    auto alloc = [&](size_t bytes) -> void* {
        void* p = ws + off;
        off += (bytes + 255) & ~(size_t)255;
        return p;
    };
    unsigned short* WhT   = (unsigned short*)alloc((size_t)H3 * H_ * 2);   // [3072][1024]
    unsigned short* WiT   = (unsigned short*)alloc((size_t)H3 * E_ * 2);   // [3072][256]
    unsigned short* WoutT = (unsigned short*)alloc((size_t)V_ * H_ * 2);   // [256][1024]
    unsigned short* embB  = (unsigned short*)alloc((size_t)V_ * E_ * 2);   // [256][256]
    unsigned short* xw    = (unsigned short*)alloc((size_t)L_ * B_ * H3 * 2); // 96 MB, [L][B][3H]
    unsigned short* yB    = (unsigned short*)alloc((size_t)B_ * L_ * H_ * 2); // 32 MB, [B][L][H]
    unsigned short* hb0   = (unsigned short*)alloc((size_t)B_ * H_ * 2);
    unsigned short* hb1   = (unsigned short*)alloc((size_t)B_ * H_ * 2);
    unsigned*       bar   = (unsigned*)alloc(1024 * sizeof(unsigned));

    prep_transpose<<<(H_ * H3 + 255) / 256, 256, 0, stream>>>(Wh, WhT, H_, H3);
    prep_transpose<<<(E_ * H3 + 255) / 256, 256, 0, stream>>>(Wi, WiT, E_, H3);
    prep_transpose<<<(H_ * V_ + 255) / 256, 256, 0, stream>>>(Wout, WoutT, H_, V_);
    prep_misc<<<(V_ * E_) / 256, 256, 0, stream>>>(emb, embB, hb0, bar);

    xw_gemm<<<dim3(48, 256), 256, 0, stream>>>(tokens, embB, WiT, xw);

    {
        unsigned short* a0 = hb0; unsigned short* a1 = hb1;
        const unsigned short* aW = WhT; const float* ab = bh;
        const unsigned short* ax = xw; unsigned short* ay = yB;
        unsigned* abar = bar;
        void* args[] = {&a0, &a1, &aW, &ab, &ax, &ay, &abar};
        hipLaunchCooperativeKernel((void*)gru_persistent, dim3(256), dim3(256),
                                   args, 0, stream);
    }

    out_gemm<<<dim3(4, 256), 256, 0, stream>>>(yB, WoutT, bout, out);
}